// Round 4
// baseline (638.145 us; speedup 1.0000x reference)
//
#include <hip/hip_runtime.h>

// biDAF attention: S = s1 s2^T, masked softmax over t2, U = P s2.
// B=32 (from in_sizes), t1=t2=D=1024, fp32 in/out.
//
// Round-4: same 4-kernel pipeline as round 3, new GEMM inner loop:
//  - double-buffered LDS (A,B x hi/lo x 2 bufs = 80 KB -> 2 blocks/CU)
//  - ONE barrier per K-step (T3-minimum 2-phase): stage(buf^1) + issue loads
//    for k+2 BEFORE the MFMA section; loads get a full phase of latency cover
//  - gemm1 converts fp32->bf16 hi/lo in-kernel (same HBM bytes as planes)
//  - gemm2 stages u16 planes (P from softmax, s2t from conv) with no VALU work
//  - conv_transpose skips j-tiles >= l2 (never read downstream)
// ws = S/P (128 MB) + s2t hi/lo (128 MB) = 256 MB; fallback to round-2 fused
// kernel if ws smaller.

typedef __attribute__((ext_vector_type(8))) short bf16x8;
typedef __attribute__((ext_vector_type(8))) unsigned short u16x8;
typedef __attribute__((ext_vector_type(4))) float f32x4;
typedef unsigned short u16;

constexpr int T1 = 1024;
constexpr int T2 = 1024;
constexpr int DD = 1024;
constexpr float NEGV = -1e30f;

__device__ __forceinline__ void split2(float x, u16& h, u16& l) {
    unsigned u = __float_as_uint(x);
    h = (u16)(u >> 16);                                  // bf16 truncation (hi)
    float r = x - __uint_as_float(u & 0xffff0000u);      // exact residual
    l = (u16)(__float_as_uint(r) >> 16);                 // bf16 truncation (lo)
}

__device__ __forceinline__ int xcd_swizzle(int bid, int nb) {
    return ((nb & 7) == 0) ? ((bid & 7) * (nb >> 3) + (bid >> 3)) : bid;
}

// ---------------- k0: s2 -> transposed bf16 hi/lo (skip j>=l2) ----------------
__global__ __launch_bounds__(256)
void conv_transpose(const float* __restrict__ s2, const int* __restrict__ l2,
                    u16* __restrict__ s2th, u16* __restrict__ s2tl)
{
    __shared__ float tile[64][65];
    int b = blockIdx.z, j0 = blockIdx.y * 64, d0 = blockIdx.x * 64;
    if (j0 >= l2[b]) return;                 // cols never read downstream
    int t = threadIdx.x;
    const float* src = s2 + ((size_t)b * T2 + j0) * DD + d0;
    #pragma unroll
    for (int rr = 0; rr < 4; ++rr) {
        int row = (t >> 4) + rr * 16, c4 = (t & 15) * 4;
        float4 v = *(const float4*)&src[(size_t)row * DD + c4];
        tile[row][c4 + 0] = v.x; tile[row][c4 + 1] = v.y;
        tile[row][c4 + 2] = v.z; tile[row][c4 + 3] = v.w;
    }
    __syncthreads();
    #pragma unroll
    for (int rr = 0; rr < 4; ++rr) {
        int d = (t >> 4) + rr * 16, j4 = (t & 15) * 4;
        ushort4 h, l;
        split2(tile[j4 + 0][d], h.x, l.x);
        split2(tile[j4 + 1][d], h.y, l.y);
        split2(tile[j4 + 2][d], h.z, l.z);
        split2(tile[j4 + 3][d], h.w, l.w);
        size_t o = ((size_t)b * DD + d0 + d) * T2 + j0 + j4;
        *(ushort4*)&s2th[o] = h;
        *(ushort4*)&s2tl[o] = l;
    }
}

// ---------------- k1: S = s1 s2^T (128x128, BK=32, dbuf, 1 barrier/step) ----------------
__global__ __launch_bounds__(256, 2)
void gemm1_qk(const float* __restrict__ s1, const int* __restrict__ l1,
              const float* __restrict__ s2, const int* __restrict__ l2,
              float* __restrict__ SP)
{
    __shared__ u16 sA[2][2][128 * 40];   // [buf][hi/lo][row*40 + k], 80B rows
    __shared__ u16 sB[2][2][128 * 40];

    int nb = (int)gridDim.x;
    int idx = xcd_swizzle((int)blockIdx.x, nb);
    int batch = idx >> 6;
    int rt = (idx >> 3) & 7, ct = idx & 7;
    int row0 = rt * 128, col0 = ct * 128;
    if (row0 >= l1[batch] || col0 >= l2[batch]) return;

    int t = (int)threadIdx.x;
    int r = t >> 1, h = t & 1;                       // staging: row, k-half(16)
    int w = t >> 6, lane = t & 63, lr = lane & 15, lg = lane >> 4;
    int wr = (w >> 1) * 64, wc = (w & 1) * 64;
    int o_st = r * 40 + h * 16;

    const float* As = s1 + ((size_t)batch * T1 + row0) * DD;
    const float* Bs = s2 + ((size_t)batch * T2 + col0) * DD;
    float* Cs = SP + ((size_t)batch * T1 + row0) * (size_t)T2 + col0;

    f32x4 acc[4][4];
    #pragma unroll
    for (int i = 0; i < 4; ++i)
        #pragma unroll
        for (int j = 0; j < 4; ++j) acc[i][j] = (f32x4)0.f;

    float4 qa[4], qb[4];
    auto loadAB = [&](int k0) {
        const float* pa = &As[(size_t)r * DD + k0 + h * 16];
        qa[0] = *(const float4*)(pa);     qa[1] = *(const float4*)(pa + 4);
        qa[2] = *(const float4*)(pa + 8); qa[3] = *(const float4*)(pa + 12);
        const float* pb = &Bs[(size_t)r * DD + k0 + h * 16];
        qb[0] = *(const float4*)(pb);     qb[1] = *(const float4*)(pb + 4);
        qb[2] = *(const float4*)(pb + 8); qb[3] = *(const float4*)(pb + 12);
    };
    auto stage = [&](int buf) {
        const float* fa = (const float*)&qa[0];
        u16x8 hh0, hh1, ll0, ll1;
        #pragma unroll
        for (int e = 0; e < 8; ++e) { u16 x, y; split2(fa[e], x, y); hh0[e] = x; ll0[e] = y; }
        #pragma unroll
        for (int e = 0; e < 8; ++e) { u16 x, y; split2(fa[8 + e], x, y); hh1[e] = x; ll1[e] = y; }
        *(u16x8*)&sA[buf][0][o_st] = hh0;  *(u16x8*)&sA[buf][0][o_st + 8] = hh1;
        *(u16x8*)&sA[buf][1][o_st] = ll0;  *(u16x8*)&sA[buf][1][o_st + 8] = ll1;
        const float* fb = (const float*)&qb[0];
        #pragma unroll
        for (int e = 0; e < 8; ++e) { u16 x, y; split2(fb[e], x, y); hh0[e] = x; ll0[e] = y; }
        #pragma unroll
        for (int e = 0; e < 8; ++e) { u16 x, y; split2(fb[8 + e], x, y); hh1[e] = x; ll1[e] = y; }
        *(u16x8*)&sB[buf][0][o_st] = hh0;  *(u16x8*)&sB[buf][0][o_st + 8] = hh1;
        *(u16x8*)&sB[buf][1][o_st] = ll0;  *(u16x8*)&sB[buf][1][o_st + 8] = ll1;
    };

    loadAB(0);
    stage(0);
    loadAB(32);
    __syncthreads();

    #pragma unroll 2
    for (int kk = 0; kk < 32; ++kk) {
        int cur = kk & 1;
        if (kk < 31) {                       // stage next, then issue k+2 loads
            stage(cur ^ 1);
            if (kk < 30) loadAB((kk + 2) * 32);
        }
        bf16x8 ah[4], al[4];
        #pragma unroll
        for (int i = 0; i < 4; ++i) {
            int o = (wr + i * 16 + lr) * 40 + lg * 8;
            ah[i] = *(const bf16x8*)&sA[cur][0][o];
            al[i] = *(const bf16x8*)&sA[cur][1][o];
        }
        #pragma unroll
        for (int j = 0; j < 4; ++j) {
            int o = (wc + j * 16 + lr) * 40 + lg * 8;
            bf16x8 bh = *(const bf16x8*)&sB[cur][0][o];
            bf16x8 bl = *(const bf16x8*)&sB[cur][1][o];
            #pragma unroll
            for (int i = 0; i < 4; ++i) {
                acc[i][j] = __builtin_amdgcn_mfma_f32_16x16x32_bf16(ah[i], bh, acc[i][j], 0, 0, 0);
                acc[i][j] = __builtin_amdgcn_mfma_f32_16x16x32_bf16(al[i], bh, acc[i][j], 0, 0, 0);
                acc[i][j] = __builtin_amdgcn_mfma_f32_16x16x32_bf16(ah[i], bl, acc[i][j], 0, 0, 0);
            }
        }
        __syncthreads();
    }

    #pragma unroll
    for (int i = 0; i < 4; ++i)
        #pragma unroll
        for (int j = 0; j < 4; ++j)
            #pragma unroll
            for (int reg = 0; reg < 4; ++reg)
                Cs[(size_t)(wr + i * 16 + 4 * lg + reg) * T2 + wc + j * 16 + lr] = acc[i][j][reg];
}

// ---------------- k2: masked softmax, P -> bf16 hi/lo in-place ----------------
__global__ __launch_bounds__(256)
void softmax_rows(float* __restrict__ SP, const int* __restrict__ l1,
                  const int* __restrict__ l2)
{
    int bid = (int)blockIdx.x;
    int batch = bid >> 5;
    int row0 = (bid & 31) * 32;
    int l1v = l1[batch], l2v = l2[batch];
    if (row0 >= l1v) return;
    int w = (int)threadIdx.x >> 6, lane = (int)threadIdx.x & 63;

    for (int i = 0; i < 8; ++i) {
        int r = row0 + w * 8 + i;
        if (r >= l1v) continue;                    // wave-uniform
        float* rowp = SP + ((size_t)batch * T1 + r) * (size_t)T2;
        float x[16];
        float m = NEGV;
        #pragma unroll
        for (int s = 0; s < 4; ++s) {
            float4 v = *(const float4*)&rowp[s * 256 + lane * 4];
            float xs[4] = {v.x, v.y, v.z, v.w};
            #pragma unroll
            for (int e = 0; e < 4; ++e) {
                int j = s * 256 + lane * 4 + e;
                float val = (j < l2v) ? xs[e] : NEGV;
                x[s * 4 + e] = val;
                m = fmaxf(m, val);
            }
        }
        #pragma unroll
        for (int off = 32; off >= 1; off >>= 1) m = fmaxf(m, __shfl_xor(m, off));
        float sum = 0.f;
        #pragma unroll
        for (int q = 0; q < 16; ++q) {
            float e = __expf(x[q] - m);            // masked -> exp(-huge)=0
            x[q] = e; sum += e;
        }
        #pragma unroll
        for (int off = 32; off >= 1; off >>= 1) sum += __shfl_xor(sum, off);
        float inv = 1.f / sum;                     // l2>=1 -> sum>=1
        u16* hi = (u16*)rowp;                      // bytes [0,2048)
        u16* lo = hi + T2;                         // bytes [2048,4096)
        #pragma unroll
        for (int s = 0; s < 4; ++s) {
            ushort4 h, l;
            split2(x[s * 4 + 0] * inv, h.x, l.x);
            split2(x[s * 4 + 1] * inv, h.y, l.y);
            split2(x[s * 4 + 2] * inv, h.z, l.z);
            split2(x[s * 4 + 3] * inv, h.w, l.w);
            *(ushort4*)&hi[s * 256 + lane * 4] = h;
            *(ushort4*)&lo[s * 256 + lane * 4] = l;
        }
    }
}

// ---------------- k3: U = P V (128x128, BK=32, dbuf, 1 barrier/step) ----------------
__global__ __launch_bounds__(256, 2)
void gemm2_pv(const float* __restrict__ SP, const u16* __restrict__ s2th,
              const u16* __restrict__ s2tl, const int* __restrict__ l1,
              const int* __restrict__ l2, float* __restrict__ out)
{
    __shared__ u16 sA[2][2][128 * 40];
    __shared__ u16 sB[2][2][128 * 40];

    int nb = (int)gridDim.x;
    int idx = xcd_swizzle((int)blockIdx.x, nb);
    int batch = idx >> 6;
    int rt = (idx >> 3) & 7, ct = idx & 7;
    int row0 = rt * 128, col0 = ct * 128;       // q-rows, d-cols
    int l1v = l1[batch], l2v = l2[batch];
    int t = (int)threadIdx.x;

    float* Co = out + ((size_t)batch * T1 + row0) * (size_t)DD + col0;

    if (row0 >= l1v) {                          // dead q-tile: write zeros
        float4 z = make_float4(0.f, 0.f, 0.f, 0.f);
        #pragma unroll
        for (int rr = 0; rr < 2; ++rr) {
            int row = (t >> 2) + rr * 64;
            #pragma unroll
            for (int ss = 0; ss < 8; ++ss)
                *(float4*)&Co[(size_t)row * DD + ((t & 3) + ss * 4) * 4] = z;
        }
        return;
    }

    int r = t >> 1, h = t & 1;
    int w = t >> 6, lane = t & 63, lr = lane & 15, lg = lane >> 4;
    int wr = (w >> 1) * 64, wc = (w & 1) * 64;
    int o_st = r * 40 + h * 16;

    const u16* Ph = (const u16*)SP;             // row q: hi at q*2048, lo +1024
    size_t prow = ((size_t)batch * T1 + row0 + r) * 2048;
    const u16* BhR = s2th + ((size_t)batch * DD + col0 + r) * (size_t)T2;
    const u16* BlR = s2tl + ((size_t)batch * DD + col0 + r) * (size_t)T2;

    f32x4 acc[4][4];
    #pragma unroll
    for (int i = 0; i < 4; ++i)
        #pragma unroll
        for (int j = 0; j < 4; ++j) acc[i][j] = (f32x4)0.f;

    int nk = (l2v + 31) >> 5;
    uint4 ra[4], rb[4];
    auto loadAB = [&](int jb) {
        size_t ba = prow + jb + h * 16;
        ra[0] = *(const uint4*)&Ph[ba];        ra[1] = *(const uint4*)&Ph[ba + 8];
        ra[2] = *(const uint4*)&Ph[ba + 1024]; ra[3] = *(const uint4*)&Ph[ba + 1032];
        size_t bb = (size_t)(jb + h * 16);
        rb[0] = *(const uint4*)&BhR[bb];       rb[1] = *(const uint4*)&BhR[bb + 8];
        rb[2] = *(const uint4*)&BlR[bb];       rb[3] = *(const uint4*)&BlR[bb + 8];
    };
    auto stage = [&](int buf) {
        *(uint4*)&sA[buf][0][o_st] = ra[0];  *(uint4*)&sA[buf][0][o_st + 8] = ra[1];
        *(uint4*)&sA[buf][1][o_st] = ra[2];  *(uint4*)&sA[buf][1][o_st + 8] = ra[3];
        *(uint4*)&sB[buf][0][o_st] = rb[0];  *(uint4*)&sB[buf][0][o_st + 8] = rb[1];
        *(uint4*)&sB[buf][1][o_st] = rb[2];  *(uint4*)&sB[buf][1][o_st + 8] = rb[3];
    };

    loadAB(0);
    stage(0);
    if (nk > 1) loadAB(32);
    __syncthreads();

    for (int kk = 0; kk < nk; ++kk) {
        int cur = kk & 1;
        if (kk + 1 < nk) {
            stage(cur ^ 1);
            if (kk + 2 < nk) loadAB((kk + 2) * 32);
        }
        bf16x8 ph[4], pl[4];
        #pragma unroll
        for (int i = 0; i < 4; ++i) {
            int o = (wr + i * 16 + lr) * 40 + lg * 8;
            ph[i] = *(const bf16x8*)&sA[cur][0][o];
            pl[i] = *(const bf16x8*)&sA[cur][1][o];
        }
        #pragma unroll
        for (int j = 0; j < 4; ++j) {
            int o = (wc + j * 16 + lr) * 40 + lg * 8;
            bf16x8 vh = *(const bf16x8*)&sB[cur][0][o];
            bf16x8 vl = *(const bf16x8*)&sB[cur][1][o];
            #pragma unroll
            for (int i = 0; i < 4; ++i) {
                acc[i][j] = __builtin_amdgcn_mfma_f32_16x16x32_bf16(ph[i], vh, acc[i][j], 0, 0, 0);
                acc[i][j] = __builtin_amdgcn_mfma_f32_16x16x32_bf16(pl[i], vh, acc[i][j], 0, 0, 0);
                acc[i][j] = __builtin_amdgcn_mfma_f32_16x16x32_bf16(ph[i], vl, acc[i][j], 0, 0, 0);
            }
        }
        __syncthreads();
    }

    #pragma unroll
    for (int i = 0; i < 4; ++i)
        #pragma unroll
        for (int reg = 0; reg < 4; ++reg) {
            int row = wr + i * 16 + 4 * lg + reg;
            bool valid = (row0 + row) < l1v;
            #pragma unroll
            for (int j = 0; j < 4; ++j)
                Co[(size_t)row * DD + wc + j * 16 + lr] = valid ? acc[i][j][reg] : 0.f;
        }
}

// ================= round-2 fused fallback (ws < 256 MB) =================
constexpr int TM = 32;
constexpr int JT = 512;
constexpr int NTH = 512;
constexpr int SB_H = 0;
constexpr int SB_L = 512 * 40;
constexpr int SA_H = 2 * 512 * 40;
constexpr int SA_L = 2 * 512 * 40 + 32 * 40;
constexpr int STAGE_U16 = 43520;

__global__ __launch_bounds__(NTH, 2)
void bidaf_mfma(const float* __restrict__ s1, const int* __restrict__ l1,
                const float* __restrict__ s2, const int* __restrict__ l2,
                const u16* __restrict__ s2th, const u16* __restrict__ s2tl,
                float* __restrict__ out)
{
    __shared__ __align__(16) float sS[TM][JT + 4];
    __shared__ __align__(16) u16 sStage[STAGE_U16];
    __shared__ float sAlpha[TM];
    __shared__ float sL[TM];

    int nblocks = (int)gridDim.x;
    int idx = xcd_swizzle((int)blockIdx.x, nblocks);
    int batch = idx >> 5, tile = idx & 31, row0 = tile * TM;
    int l1v = l1[batch], l2v = l2[batch];
    int tid = (int)threadIdx.x;
    float* outTile = out + ((size_t)batch * T1 + row0) * DD;

    if (row0 >= l1v) {
        float4 z4 = make_float4(0.f, 0.f, 0.f, 0.f);
        float4* o4 = (float4*)outTile;
        for (int i = tid; i < TM * DD / 4; i += NTH) o4[i] = z4;
        return;
    }
    int w = tid >> 6, lane = tid & 63, lg = lane >> 4, lr = lane & 15;
    const float* s1b = s1 + ((size_t)batch * T1 + row0) * DD;
    const float* s2b = s2 + (size_t)batch * T2 * DD;
    const u16* th = s2th + (size_t)batch * (size_t)T2 * DD;
    const u16* tl = s2tl + (size_t)batch * (size_t)T2 * DD;

    f32x4 uacc[2][8];
    #pragma unroll
    for (int a = 0; a < 2; ++a)
        #pragma unroll
        for (int c = 0; c < 8; ++c) uacc[a][c] = (f32x4)0.f;
    float m_[4] = {NEGV, NEGV, NEGV, NEGV};
    float l_[4] = {0.f, 0.f, 0.f, 0.f};

    int njt = (l2v + JT - 1) / JT;
    for (int jt = 0; jt < njt; ++jt) {
        int j0 = jt * JT;
        f32x4 sacc[2][4];
        #pragma unroll
        for (int a = 0; a < 2; ++a)
            #pragma unroll
            for (int c = 0; c < 4; ++c) sacc[a][c] = (f32x4)0.f;

        float4 pfB[8]; float4 pfA;
        #pragma unroll
        for (int g = 0; g < 8; ++g) {
            int row = (tid >> 3) + g * 64, s = tid & 7;
            pfB[g] = *(const float4*)&s2b[(size_t)(j0 + row) * DD + s * 4];
        }
        if (tid < 256) { int row = tid >> 3, s = tid & 7;
            pfA = *(const float4*)&s1b[(size_t)row * DD + s * 4]; }

        for (int k0 = 0; k0 < DD; k0 += 32) {
            __syncthreads();
            #pragma unroll
            for (int g = 0; g < 8; ++g) {
                int row = (tid >> 3) + g * 64, s = tid & 7;
                ushort4 h, l;
                split2(pfB[g].x, h.x, l.x); split2(pfB[g].y, h.y, l.y);
                split2(pfB[g].z, h.z, l.z); split2(pfB[g].w, h.w, l.w);
                *(ushort4*)&sStage[SB_H + row * 40 + s * 4] = h;
                *(ushort4*)&sStage[SB_L + row * 40 + s * 4] = l;
            }
            if (tid < 256) {
                int row = tid >> 3, s = tid & 7;
                ushort4 h, l;
                split2(pfA.x, h.x, l.x); split2(pfA.y, h.y, l.y);
                split2(pfA.z, h.z, l.z); split2(pfA.w, h.w, l.w);
                *(ushort4*)&sStage[SA_H + row * 40 + s * 4] = h;
                *(ushort4*)&sStage[SA_L + row * 40 + s * 4] = l;
            }
            if (k0 + 32 < DD) {
                int kn = k0 + 32;
                #pragma unroll
                for (int g = 0; g < 8; ++g) {
                    int row = (tid >> 3) + g * 64, s = tid & 7;
                    pfB[g] = *(const float4*)&s2b[(size_t)(j0 + row) * DD + kn + s * 4];
                }
                if (tid < 256) { int row = tid >> 3, s = tid & 7;
                    pfA = *(const float4*)&s1b[(size_t)row * DD + kn + s * 4]; }
            }
            __syncthreads();
            bf16x8 ah[2], al[2];
            #pragma unroll
            for (int rf = 0; rf < 2; ++rf) {
                ah[rf] = *(bf16x8*)&sStage[SA_H + (rf * 16 + lr) * 40 + lg * 8];
                al[rf] = *(bf16x8*)&sStage[SA_L + (rf * 16 + lr) * 40 + lg * 8];
            }
            #pragma unroll
            for (int jf = 0; jf < 4; ++jf) {
                int jr = w * 64 + jf * 16 + lr;
                bf16x8 bh = *(bf16x8*)&sStage[SB_H + jr * 40 + lg * 8];
                bf16x8 bl = *(bf16x8*)&sStage[SB_L + jr * 40 + lg * 8];
                #pragma unroll
                for (int rf = 0; rf < 2; ++rf) {
                    sacc[rf][jf] = __builtin_amdgcn_mfma_f32_16x16x32_bf16(ah[rf], bh, sacc[rf][jf], 0, 0, 0);
                    sacc[rf][jf] = __builtin_amdgcn_mfma_f32_16x16x32_bf16(ah[rf], bl, sacc[rf][jf], 0, 0, 0);
                    sacc[rf][jf] = __builtin_amdgcn_mfma_f32_16x16x32_bf16(al[rf], bh, sacc[rf][jf], 0, 0, 0);
                }
            }
        }
        __syncthreads();
        #pragma unroll
        for (int rf = 0; rf < 2; ++rf)
            #pragma unroll
            for (int jf = 0; jf < 4; ++jf)
                #pragma unroll
                for (int reg = 0; reg < 4; ++reg)
                    sS[rf * 16 + 4 * lg + reg][w * 64 + jf * 16 + lr] = sacc[rf][jf][reg];
        __syncthreads();

        #pragma unroll
        for (int i = 0; i < 4; ++i) {
            int r = w * 4 + i;
            float v[8]; float mt = NEGV;
            #pragma unroll
            for (int q = 0; q < 8; ++q) {
                int jj = q * 64 + lane;
                float x = sS[r][jj];
                x = (j0 + jj < l2v) ? x : NEGV;
                v[q] = x; mt = fmaxf(mt, x);
            }
            #pragma unroll
            for (int off = 32; off >= 1; off >>= 1) mt = fmaxf(mt, __shfl_xor(mt, off));
            float mn = fmaxf(m_[i], mt);
            float alp = __expf(m_[i] - mn);
            float e[8]; float ps = 0.f;
            #pragma unroll
            for (int q = 0; q < 8; ++q) {
                int jj = q * 64 + lane;
                float x = (j0 + jj < l2v) ? __expf(v[q] - mn) : 0.f;
                e[q] = x; ps += x;
            }
            asm volatile("" ::: "memory");
            u16* rowp = (u16*)&sS[r][0];
            #pragma unroll
            for (int q = 0; q < 8; ++q) {
                int jj = q * 64 + lane;
                u16 hh, lo;
                split2(e[q], hh, lo);
                rowp[jj] = hh;
                rowp[JT + jj] = lo;
            }
            #pragma unroll
            for (int off = 32; off >= 1; off >>= 1) ps += __shfl_xor(ps, off);
            l_[i] = l_[i] * alp + ps;
            m_[i] = mn;
            if (lane == 0) sAlpha[r] = alp;
        }
        __syncthreads();

        #pragma unroll
        for (int rf = 0; rf < 2; ++rf)
            #pragma unroll
            for (int reg = 0; reg < 4; ++reg) {
                float f = sAlpha[rf * 16 + 4 * lg + reg];
                #pragma unroll
                for (int df = 0; df < 8; ++df) uacc[rf][df][reg] *= f;
            }

        int rem = l2v - j0; if (rem > JT) rem = JT;
        int njc = (rem + 31) / 32;
        for (int jc = 0; jc < njc; ++jc) {
            int jb = j0 + jc * 32;
            #pragma unroll
            for (int p = 0; p < 2; ++p) {
                const u16* src = p ? tl : th;
                uint4 pv[8];
                #pragma unroll
                for (int g = 0; g < 8; ++g) {
                    int dr = (tid >> 2) + g * 128, s = tid & 3;
                    pv[g] = *(const uint4*)&src[(size_t)dr * T2 + jb + s * 8];
                }
                __syncthreads();
                #pragma unroll
                for (int g = 0; g < 8; ++g) {
                    int dr = (tid >> 2) + g * 128, s = tid & 3;
                    *(uint4*)&sStage[dr * 40 + s * 8] = pv[g];
                }
                __syncthreads();
                bf16x8 pah[2], pal[2];
                #pragma unroll
                for (int rf = 0; rf < 2; ++rf) {
                    const char* rowb = (const char*)&sS[rf * 16 + lr][0];
                    pah[rf] = *(const bf16x8*)(rowb + (size_t)(jc * 32 + lg * 8) * 2);
                    if (p == 0)
                        pal[rf] = *(const bf16x8*)(rowb + (size_t)(JT + jc * 32 + lg * 8) * 2);
                }
                #pragma unroll
                for (int df = 0; df < 8; ++df) {
                    bf16x8 vb = *(bf16x8*)&sStage[(w * 128 + df * 16 + lr) * 40 + lg * 8];
                    #pragma unroll
                    for (int rf = 0; rf < 2; ++rf) {
                        uacc[rf][df] = __builtin_amdgcn_mfma_f32_16x16x32_bf16(pah[rf], vb, uacc[rf][df], 0, 0, 0);
                        if (p == 0)
                            uacc[rf][df] = __builtin_amdgcn_mfma_f32_16x16x32_bf16(pal[rf], vb, uacc[rf][df], 0, 0, 0);
                    }
                }
            }
        }
        __syncthreads();
    }

    if (lane == 0) {
        #pragma unroll
        for (int i = 0; i < 4; ++i) sL[w * 4 + i] = l_[i];
    }
    __syncthreads();
    #pragma unroll
    for (int rf = 0; rf < 2; ++rf)
        #pragma unroll
        for (int reg = 0; reg < 4; ++reg) {
            int r = rf * 16 + 4 * lg + reg;
            float inv = 1.0f / sL[r];
            bool valid = (row0 + r) < l1v;
            #pragma unroll
            for (int df = 0; df < 8; ++df) {
                int d = w * 128 + df * 16 + lr;
                outTile[(size_t)r * DD + d] = valid ? uacc[rf][df][reg] * inv : 0.f;
            }
        }
}

extern "C" void kernel_launch(void* const* d_in, const int* in_sizes, int n_in,
                              void* d_out, int out_size, void* d_ws, size_t ws_size,
                              hipStream_t stream)
{
    const float* s1 = (const float*)d_in[0];
    const int* l1 = (const int*)d_in[1];
    const float* s2 = (const float*)d_in[2];
    const int* l2 = (const int*)d_in[3];
    float* outp = (float*)d_out;

    int B = in_sizes[1];
    size_t elems = (size_t)B * T2 * DD;
    size_t sp_bytes = (size_t)B * T1 * T2 * sizeof(float);     // 128 MB
    size_t t_bytes = elems * 2 * sizeof(u16);                  // 128 MB (hi+lo)

    if (ws_size >= sp_bytes + t_bytes) {
        float* SP = (float*)d_ws;
        u16* s2th = (u16*)((char*)d_ws + sp_bytes);
        u16* s2tl = s2th + elems;
        conv_transpose<<<dim3(DD / 64, T2 / 64, B), 256, 0, stream>>>(s2, l2, s2th, s2tl);
        gemm1_qk<<<dim3(B * 64), 256, 0, stream>>>(s1, l1, s2, l2, SP);
        softmax_rows<<<dim3(B * 32), 256, 0, stream>>>(SP, l1, l2);
        gemm2_pv<<<dim3(B * 64), 256, 0, stream>>>(SP, s2th, s2tl, l1, l2, outp);
    } else {
        u16* s2th = (u16*)d_ws;
        u16* s2tl = s2th + elems;
        conv_transpose<<<dim3(DD / 64, T2 / 64, B), 256, 0, stream>>>(s2, l2, s2th, s2tl);
        bidaf_mfma<<<dim3(B * 32), NTH, 0, stream>>>(s1, l1, s2, l2, s2th, s2tl, outp);
    }
}

// Round 5
// 334.833 us; speedup vs baseline: 1.9059x; 1.9059x over previous
//
#include <hip/hip_runtime.h>

// biDAF attention: S = s1 s2^T, masked softmax over t2, U = P s2.
// B=32 (from in_sizes), t1=t2=D=1024, fp32 in/out.
//
// Round-5: round-3 pipeline (proven 357 us) with ONE scheduling change:
//  - NO xcd swizzle in the GEMMs. Default blockIdx round-robins across XCDs,
//    so every batch's tiles spread over all 8 XCDs -> no straggler XCD.
//    (Round-3's swizzle confined 4 whole batches per XCD; valid-tile count
//    per batch varies 1..64 -> up to ~8x work imbalance across XCDs.)
//  - conv_transpose skips j-tiles >= l2 (kept from round 4; cols never read).
// Round-4's dbuf/lambda restructure is fully reverted (it spilled prefetch
// regs to scratch: WRITE_SIZE 131->590 MB, gemm2 158->424 us).
// ws = S/P (128 MB) + s2t hi/lo (128 MB) = 256 MB; fallback: fused kernel.

typedef __attribute__((ext_vector_type(8))) short bf16x8;
typedef __attribute__((ext_vector_type(4))) float f32x4;
typedef unsigned short u16;

constexpr int T1 = 1024;
constexpr int T2 = 1024;
constexpr int DD = 1024;
constexpr float NEGV = -1e30f;

__device__ __forceinline__ void split2(float x, u16& h, u16& l) {
    unsigned u = __float_as_uint(x);
    h = (u16)(u >> 16);                                  // bf16 truncation (hi)
    float r = x - __uint_as_float(u & 0xffff0000u);      // exact residual
    l = (u16)(__float_as_uint(r) >> 16);                 // bf16 truncation (lo)
}

__device__ __forceinline__ int xcd_swizzle(int bid, int nb) {
    return ((nb & 7) == 0) ? ((bid & 7) * (nb >> 3) + (bid >> 3)) : bid;
}

// ---------------- k0: s2 -> transposed bf16 hi/lo (skip j>=l2) ----------------
__global__ __launch_bounds__(256)
void conv_transpose(const float* __restrict__ s2, const int* __restrict__ l2,
                    u16* __restrict__ s2th, u16* __restrict__ s2tl)
{
    __shared__ float tile[64][65];
    int b = blockIdx.z, j0 = blockIdx.y * 64, d0 = blockIdx.x * 64;
    if (j0 >= l2[b]) return;                 // cols never read downstream
    int t = threadIdx.x;
    const float* src = s2 + ((size_t)b * T2 + j0) * DD + d0;
    #pragma unroll
    for (int rr = 0; rr < 4; ++rr) {
        int row = (t >> 4) + rr * 16, c4 = (t & 15) * 4;
        float4 v = *(const float4*)&src[(size_t)row * DD + c4];
        tile[row][c4 + 0] = v.x; tile[row][c4 + 1] = v.y;
        tile[row][c4 + 2] = v.z; tile[row][c4 + 3] = v.w;
    }
    __syncthreads();
    #pragma unroll
    for (int rr = 0; rr < 4; ++rr) {
        int d = (t >> 4) + rr * 16, j4 = (t & 15) * 4;
        ushort4 h, l;
        split2(tile[j4 + 0][d], h.x, l.x);
        split2(tile[j4 + 1][d], h.y, l.y);
        split2(tile[j4 + 2][d], h.z, l.z);
        split2(tile[j4 + 3][d], h.w, l.w);
        size_t o = ((size_t)b * DD + d0 + d) * T2 + j0 + j4;
        *(ushort4*)&s2th[o] = h;
        *(ushort4*)&s2tl[o] = l;
    }
}

// ---------------- k1: S = s1 s2^T (128x128 tile, bf16x3) ----------------
// LDS rows: 32 data u16 + 8 pad (80 B stride -> <=2-way bank aliasing)
__global__ __launch_bounds__(256, 2)
void gemm1_qk(const float* __restrict__ s1, const int* __restrict__ l1,
              const float* __restrict__ s2, const int* __restrict__ l2,
              float* __restrict__ SP)
{
    __shared__ u16 sAh[128 * 40], sAl[128 * 40], sBh[128 * 40], sBl[128 * 40];

    int idx = (int)blockIdx.x;              // natural order: HW round-robins XCDs
    int batch = idx >> 6;
    int rt = (idx >> 3) & 7, ct = idx & 7;
    int row0 = rt * 128, col0 = ct * 128;
    if (row0 >= l1[batch] || col0 >= l2[batch]) return;

    int t = (int)threadIdx.x;
    int lrow = t >> 2, lslot = t & 3;
    int w = t >> 6, lane = t & 63, lr = lane & 15, lg = lane >> 4;
    int wr = (w >> 1) * 64, wc = (w & 1) * 64;

    const float* As = s1 + ((size_t)batch * T1 + row0) * DD;
    const float* Bs = s2 + ((size_t)batch * T2 + col0) * DD;
    float* Cs = SP + ((size_t)batch * T1 + row0) * (size_t)T2 + col0;

    f32x4 acc[4][4];
    #pragma unroll
    for (int i = 0; i < 4; ++i)
        #pragma unroll
        for (int j = 0; j < 4; ++j) acc[i][j] = (f32x4)0.f;

    float4 pA[4], pB[4];
    #pragma unroll
    for (int rr = 0; rr < 2; ++rr)
        #pragma unroll
        for (int ss = 0; ss < 2; ++ss) {
            pA[rr * 2 + ss] = *(const float4*)&As[(size_t)(lrow + rr * 64) * DD + (lslot + ss * 4) * 4];
            pB[rr * 2 + ss] = *(const float4*)&Bs[(size_t)(lrow + rr * 64) * DD + (lslot + ss * 4) * 4];
        }

    for (int k0 = 0; k0 < DD; k0 += 32) {
        __syncthreads();
        #pragma unroll
        for (int rr = 0; rr < 2; ++rr)
            #pragma unroll
            for (int ss = 0; ss < 2; ++ss) {
                int o = (lrow + rr * 64) * 40 + (lslot + ss * 4) * 4;
                float4 va = pA[rr * 2 + ss];
                ushort4 h, l;
                split2(va.x, h.x, l.x); split2(va.y, h.y, l.y);
                split2(va.z, h.z, l.z); split2(va.w, h.w, l.w);
                *(ushort4*)&sAh[o] = h; *(ushort4*)&sAl[o] = l;
                float4 vb = pB[rr * 2 + ss];
                split2(vb.x, h.x, l.x); split2(vb.y, h.y, l.y);
                split2(vb.z, h.z, l.z); split2(vb.w, h.w, l.w);
                *(ushort4*)&sBh[o] = h; *(ushort4*)&sBl[o] = l;
            }
        if (k0 + 32 < DD) {          // prefetch next chunk; lands under MFMA
            int kn = k0 + 32;
            #pragma unroll
            for (int rr = 0; rr < 2; ++rr)
                #pragma unroll
                for (int ss = 0; ss < 2; ++ss) {
                    pA[rr * 2 + ss] = *(const float4*)&As[(size_t)(lrow + rr * 64) * DD + kn + (lslot + ss * 4) * 4];
                    pB[rr * 2 + ss] = *(const float4*)&Bs[(size_t)(lrow + rr * 64) * DD + kn + (lslot + ss * 4) * 4];
                }
        }
        __syncthreads();
        bf16x8 ah[4], al[4];
        #pragma unroll
        for (int i = 0; i < 4; ++i) {
            int o = (wr + i * 16 + lr) * 40 + lg * 8;
            ah[i] = *(const bf16x8*)&sAh[o];
            al[i] = *(const bf16x8*)&sAl[o];
        }
        #pragma unroll
        for (int j = 0; j < 4; ++j) {
            int o = (wc + j * 16 + lr) * 40 + lg * 8;
            bf16x8 bh = *(const bf16x8*)&sBh[o];
            bf16x8 bl = *(const bf16x8*)&sBl[o];
            #pragma unroll
            for (int i = 0; i < 4; ++i) {
                acc[i][j] = __builtin_amdgcn_mfma_f32_16x16x32_bf16(ah[i], bh, acc[i][j], 0, 0, 0);
                acc[i][j] = __builtin_amdgcn_mfma_f32_16x16x32_bf16(al[i], bh, acc[i][j], 0, 0, 0);
                acc[i][j] = __builtin_amdgcn_mfma_f32_16x16x32_bf16(ah[i], bl, acc[i][j], 0, 0, 0);
            }
        }
    }
    #pragma unroll
    for (int i = 0; i < 4; ++i)
        #pragma unroll
        for (int j = 0; j < 4; ++j)
            #pragma unroll
            for (int reg = 0; reg < 4; ++reg)
                Cs[(size_t)(wr + i * 16 + 4 * lg + reg) * T2 + wc + j * 16 + lr] = acc[i][j][reg];
}

// ---------------- k2: masked softmax, P -> bf16 hi/lo in-place ----------------
__global__ __launch_bounds__(256)
void softmax_rows(float* __restrict__ SP, const int* __restrict__ l1,
                  const int* __restrict__ l2)
{
    int bid = (int)blockIdx.x;
    int batch = bid >> 5;
    int row0 = (bid & 31) * 32;
    int l1v = l1[batch], l2v = l2[batch];
    if (row0 >= l1v) return;
    int w = (int)threadIdx.x >> 6, lane = (int)threadIdx.x & 63;

    for (int i = 0; i < 8; ++i) {
        int r = row0 + w * 8 + i;
        if (r >= l1v) continue;                    // wave-uniform
        float* rowp = SP + ((size_t)batch * T1 + r) * (size_t)T2;
        float x[16];
        float m = NEGV;
        #pragma unroll
        for (int s = 0; s < 4; ++s) {
            float4 v = *(const float4*)&rowp[s * 256 + lane * 4];
            float xs[4] = {v.x, v.y, v.z, v.w};
            #pragma unroll
            for (int e = 0; e < 4; ++e) {
                int j = s * 256 + lane * 4 + e;
                float val = (j < l2v) ? xs[e] : NEGV;
                x[s * 4 + e] = val;
                m = fmaxf(m, val);
            }
        }
        #pragma unroll
        for (int off = 32; off >= 1; off >>= 1) m = fmaxf(m, __shfl_xor(m, off));
        float sum = 0.f;
        #pragma unroll
        for (int q = 0; q < 16; ++q) {
            float e = __expf(x[q] - m);            // masked -> exp(-huge)=0
            x[q] = e; sum += e;
        }
        #pragma unroll
        for (int off = 32; off >= 1; off >>= 1) sum += __shfl_xor(sum, off);
        float inv = 1.f / sum;                     // l2>=1 -> sum>=1
        u16* hi = (u16*)rowp;                      // bytes [0,2048)
        u16* lo = hi + T2;                         // bytes [2048,4096)
        #pragma unroll
        for (int s = 0; s < 4; ++s) {
            ushort4 h, l;
            split2(x[s * 4 + 0] * inv, h.x, l.x);
            split2(x[s * 4 + 1] * inv, h.y, l.y);
            split2(x[s * 4 + 2] * inv, h.z, l.z);
            split2(x[s * 4 + 3] * inv, h.w, l.w);
            *(ushort4*)&hi[s * 256 + lane * 4] = h;
            *(ushort4*)&lo[s * 256 + lane * 4] = l;
        }
    }
}

// ---------------- k3: U = P V (128x128 tile, bf16x3) ----------------
__global__ __launch_bounds__(256, 2)
void gemm2_pv(const float* __restrict__ SP, const u16* __restrict__ s2th,
              const u16* __restrict__ s2tl, const int* __restrict__ l1,
              const int* __restrict__ l2, float* __restrict__ out)
{
    __shared__ u16 sAh[128 * 40], sAl[128 * 40], sBh[128 * 40], sBl[128 * 40];

    int idx = (int)blockIdx.x;              // natural order: HW round-robins XCDs
    int batch = idx >> 6;
    int rt = (idx >> 3) & 7, ct = idx & 7;
    int row0 = rt * 128, col0 = ct * 128;   // q-rows, d-cols
    int l1v = l1[batch], l2v = l2[batch];
    int t = (int)threadIdx.x;

    float* Co = out + ((size_t)batch * T1 + row0) * (size_t)DD + col0;

    if (row0 >= l1v) {                      // dead q-tile: write zeros
        float4 z = make_float4(0.f, 0.f, 0.f, 0.f);
        #pragma unroll
        for (int rr = 0; rr < 2; ++rr) {
            int row = (t >> 2) + rr * 64;
            #pragma unroll
            for (int ss = 0; ss < 8; ++ss)
                *(float4*)&Co[(size_t)row * DD + ((t & 3) + ss * 4) * 4] = z;
        }
        return;
    }

    int lrow = t >> 2, lslot = t & 3;
    int w = t >> 6, lane = t & 63, lr = lane & 15, lg = lane >> 4;
    int wr = (w >> 1) * 64, wc = (w & 1) * 64;

    const u16* Pb = (const u16*)SP;         // row q: hi at q*2048, lo at +1024
    size_t arow = ((size_t)batch * T1 + row0);
    const u16* Bh_g = s2th + ((size_t)batch * DD + col0) * (size_t)T2;
    const u16* Bl_g = s2tl + ((size_t)batch * DD + col0) * (size_t)T2;

    f32x4 acc[4][4];
    #pragma unroll
    for (int i = 0; i < 4; ++i)
        #pragma unroll
        for (int j = 0; j < 4; ++j) acc[i][j] = (f32x4)0.f;

    int nk = (l2v + 31) >> 5;
    ushort4 pAh[4], pAl[4], pBh[4], pBl[4];
    #pragma unroll
    for (int rr = 0; rr < 2; ++rr)
        #pragma unroll
        for (int ss = 0; ss < 2; ++ss) {
            int q = lrow + rr * 64, s4 = (lslot + ss * 4) * 4;
            pAh[rr * 2 + ss] = *(const ushort4*)&Pb[(arow + q) * 2048 + s4];
            pAl[rr * 2 + ss] = *(const ushort4*)&Pb[(arow + q) * 2048 + 1024 + s4];
            pBh[rr * 2 + ss] = *(const ushort4*)&Bh_g[(size_t)q * T2 + s4];
            pBl[rr * 2 + ss] = *(const ushort4*)&Bl_g[(size_t)q * T2 + s4];
        }

    for (int kk = 0; kk < nk; ++kk) {
        __syncthreads();
        #pragma unroll
        for (int rr = 0; rr < 2; ++rr)
            #pragma unroll
            for (int ss = 0; ss < 2; ++ss) {
                int o = (lrow + rr * 64) * 40 + (lslot + ss * 4) * 4;
                *(ushort4*)&sAh[o] = pAh[rr * 2 + ss];
                *(ushort4*)&sAl[o] = pAl[rr * 2 + ss];
                *(ushort4*)&sBh[o] = pBh[rr * 2 + ss];
                *(ushort4*)&sBl[o] = pBl[rr * 2 + ss];
            }
        if (kk + 1 < nk) {
            int kn = (kk + 1) * 32;
            #pragma unroll
            for (int rr = 0; rr < 2; ++rr)
                #pragma unroll
                for (int ss = 0; ss < 2; ++ss) {
                    int q = lrow + rr * 64, s4 = kn + (lslot + ss * 4) * 4;
                    pAh[rr * 2 + ss] = *(const ushort4*)&Pb[(arow + q) * 2048 + s4];
                    pAl[rr * 2 + ss] = *(const ushort4*)&Pb[(arow + q) * 2048 + 1024 + s4];
                    pBh[rr * 2 + ss] = *(const ushort4*)&Bh_g[(size_t)q * T2 + s4];
                    pBl[rr * 2 + ss] = *(const ushort4*)&Bl_g[(size_t)q * T2 + s4];
                }
        }
        __syncthreads();
        bf16x8 ph[4], pl[4];
        #pragma unroll
        for (int i = 0; i < 4; ++i) {
            int o = (wr + i * 16 + lr) * 40 + lg * 8;
            ph[i] = *(const bf16x8*)&sAh[o];
            pl[i] = *(const bf16x8*)&sAl[o];
        }
        #pragma unroll
        for (int j = 0; j < 4; ++j) {
            int o = (wc + j * 16 + lr) * 40 + lg * 8;
            bf16x8 vh = *(const bf16x8*)&sBh[o];
            bf16x8 vl = *(const bf16x8*)&sBl[o];
            #pragma unroll
            for (int i = 0; i < 4; ++i) {
                acc[i][j] = __builtin_amdgcn_mfma_f32_16x16x32_bf16(ph[i], vh, acc[i][j], 0, 0, 0);
                acc[i][j] = __builtin_amdgcn_mfma_f32_16x16x32_bf16(pl[i], vh, acc[i][j], 0, 0, 0);
                acc[i][j] = __builtin_amdgcn_mfma_f32_16x16x32_bf16(ph[i], vl, acc[i][j], 0, 0, 0);
            }
        }
    }
    #pragma unroll
    for (int i = 0; i < 4; ++i)
        #pragma unroll
        for (int reg = 0; reg < 4; ++reg) {
            int row = wr + i * 16 + 4 * lg + reg;
            bool valid = (row0 + row) < l1v;
            #pragma unroll
            for (int j = 0; j < 4; ++j)
                Co[(size_t)row * DD + wc + j * 16 + lr] = valid ? acc[i][j][reg] : 0.f;
        }
}

// ================= round-2 fused fallback (ws < 256 MB) =================
constexpr int TM = 32;
constexpr int JT = 512;
constexpr int NTH = 512;
constexpr int SB_H = 0;
constexpr int SB_L = 512 * 40;
constexpr int SA_H = 2 * 512 * 40;
constexpr int SA_L = 2 * 512 * 40 + 32 * 40;
constexpr int STAGE_U16 = 43520;

__global__ __launch_bounds__(NTH, 2)
void bidaf_mfma(const float* __restrict__ s1, const int* __restrict__ l1,
                const float* __restrict__ s2, const int* __restrict__ l2,
                const u16* __restrict__ s2th, const u16* __restrict__ s2tl,
                float* __restrict__ out)
{
    __shared__ __align__(16) float sS[TM][JT + 4];
    __shared__ __align__(16) u16 sStage[STAGE_U16];
    __shared__ float sAlpha[TM];
    __shared__ float sL[TM];

    int nblocks = (int)gridDim.x;
    int idx = xcd_swizzle((int)blockIdx.x, nblocks);
    int batch = idx >> 5, tile = idx & 31, row0 = tile * TM;
    int l1v = l1[batch], l2v = l2[batch];
    int tid = (int)threadIdx.x;
    float* outTile = out + ((size_t)batch * T1 + row0) * DD;

    if (row0 >= l1v) {
        float4 z4 = make_float4(0.f, 0.f, 0.f, 0.f);
        float4* o4 = (float4*)outTile;
        for (int i = tid; i < TM * DD / 4; i += NTH) o4[i] = z4;
        return;
    }
    int w = tid >> 6, lane = tid & 63, lg = lane >> 4, lr = lane & 15;
    const float* s1b = s1 + ((size_t)batch * T1 + row0) * DD;
    const float* s2b = s2 + (size_t)batch * T2 * DD;
    const u16* th = s2th + (size_t)batch * (size_t)T2 * DD;
    const u16* tl = s2tl + (size_t)batch * (size_t)T2 * DD;

    f32x4 uacc[2][8];
    #pragma unroll
    for (int a = 0; a < 2; ++a)
        #pragma unroll
        for (int c = 0; c < 8; ++c) uacc[a][c] = (f32x4)0.f;
    float m_[4] = {NEGV, NEGV, NEGV, NEGV};
    float l_[4] = {0.f, 0.f, 0.f, 0.f};

    int njt = (l2v + JT - 1) / JT;
    for (int jt = 0; jt < njt; ++jt) {
        int j0 = jt * JT;
        f32x4 sacc[2][4];
        #pragma unroll
        for (int a = 0; a < 2; ++a)
            #pragma unroll
            for (int c = 0; c < 4; ++c) sacc[a][c] = (f32x4)0.f;

        float4 pfB[8]; float4 pfA;
        #pragma unroll
        for (int g = 0; g < 8; ++g) {
            int row = (tid >> 3) + g * 64, s = tid & 7;
            pfB[g] = *(const float4*)&s2b[(size_t)(j0 + row) * DD + s * 4];
        }
        if (tid < 256) { int row = tid >> 3, s = tid & 7;
            pfA = *(const float4*)&s1b[(size_t)row * DD + s * 4]; }

        for (int k0 = 0; k0 < DD; k0 += 32) {
            __syncthreads();
            #pragma unroll
            for (int g = 0; g < 8; ++g) {
                int row = (tid >> 3) + g * 64, s = tid & 7;
                ushort4 h, l;
                split2(pfB[g].x, h.x, l.x); split2(pfB[g].y, h.y, l.y);
                split2(pfB[g].z, h.z, l.z); split2(pfB[g].w, h.w, l.w);
                *(ushort4*)&sStage[SB_H + row * 40 + s * 4] = h;
                *(ushort4*)&sStage[SB_L + row * 40 + s * 4] = l;
            }
            if (tid < 256) {
                int row = tid >> 3, s = tid & 7;
                ushort4 h, l;
                split2(pfA.x, h.x, l.x); split2(pfA.y, h.y, l.y);
                split2(pfA.z, h.z, l.z); split2(pfA.w, h.w, l.w);
                *(ushort4*)&sStage[SA_H + row * 40 + s * 4] = h;
                *(ushort4*)&sStage[SA_L + row * 40 + s * 4] = l;
            }
            if (k0 + 32 < DD) {
                int kn = k0 + 32;
                #pragma unroll
                for (int g = 0; g < 8; ++g) {
                    int row = (tid >> 3) + g * 64, s = tid & 7;
                    pfB[g] = *(const float4*)&s2b[(size_t)(j0 + row) * DD + kn + s * 4];
                }
                if (tid < 256) { int row = tid >> 3, s = tid & 7;
                    pfA = *(const float4*)&s1b[(size_t)row * DD + kn + s * 4]; }
            }
            __syncthreads();
            bf16x8 ah[2], al[2];
            #pragma unroll
            for (int rf = 0; rf < 2; ++rf) {
                ah[rf] = *(bf16x8*)&sStage[SA_H + (rf * 16 + lr) * 40 + lg * 8];
                al[rf] = *(bf16x8*)&sStage[SA_L + (rf * 16 + lr) * 40 + lg * 8];
            }
            #pragma unroll
            for (int jf = 0; jf < 4; ++jf) {
                int jr = w * 64 + jf * 16 + lr;
                bf16x8 bh = *(bf16x8*)&sStage[SB_H + jr * 40 + lg * 8];
                bf16x8 bl = *(bf16x8*)&sStage[SB_L + jr * 40 + lg * 8];
                #pragma unroll
                for (int rf = 0; rf < 2; ++rf) {
                    sacc[rf][jf] = __builtin_amdgcn_mfma_f32_16x16x32_bf16(ah[rf], bh, sacc[rf][jf], 0, 0, 0);
                    sacc[rf][jf] = __builtin_amdgcn_mfma_f32_16x16x32_bf16(ah[rf], bl, sacc[rf][jf], 0, 0, 0);
                    sacc[rf][jf] = __builtin_amdgcn_mfma_f32_16x16x32_bf16(al[rf], bh, sacc[rf][jf], 0, 0, 0);
                }
            }
        }
        __syncthreads();
        #pragma unroll
        for (int rf = 0; rf < 2; ++rf)
            #pragma unroll
            for (int jf = 0; jf < 4; ++jf)
                #pragma unroll
                for (int reg = 0; reg < 4; ++reg)
                    sS[rf * 16 + 4 * lg + reg][w * 64 + jf * 16 + lr] = sacc[rf][jf][reg];
        __syncthreads();

        #pragma unroll
        for (int i = 0; i < 4; ++i) {
            int r = w * 4 + i;
            float v[8]; float mt = NEGV;
            #pragma unroll
            for (int q = 0; q < 8; ++q) {
                int jj = q * 64 + lane;
                float x = sS[r][jj];
                x = (j0 + jj < l2v) ? x : NEGV;
                v[q] = x; mt = fmaxf(mt, x);
            }
            #pragma unroll
            for (int off = 32; off >= 1; off >>= 1) mt = fmaxf(mt, __shfl_xor(mt, off));
            float mn = fmaxf(m_[i], mt);
            float alp = __expf(m_[i] - mn);
            float e[8]; float ps = 0.f;
            #pragma unroll
            for (int q = 0; q < 8; ++q) {
                int jj = q * 64 + lane;
                float x = (j0 + jj < l2v) ? __expf(v[q] - mn) : 0.f;
                e[q] = x; ps += x;
            }
            asm volatile("" ::: "memory");
            u16* rowp = (u16*)&sS[r][0];
            #pragma unroll
            for (int q = 0; q < 8; ++q) {
                int jj = q * 64 + lane;
                u16 hh, lo;
                split2(e[q], hh, lo);
                rowp[jj] = hh;
                rowp[JT + jj] = lo;
            }
            #pragma unroll
            for (int off = 32; off >= 1; off >>= 1) ps += __shfl_xor(ps, off);
            l_[i] = l_[i] * alp + ps;
            m_[i] = mn;
            if (lane == 0) sAlpha[r] = alp;
        }
        __syncthreads();

        #pragma unroll
        for (int rf = 0; rf < 2; ++rf)
            #pragma unroll
            for (int reg = 0; reg < 4; ++reg) {
                float f = sAlpha[rf * 16 + 4 * lg + reg];
                #pragma unroll
                for (int df = 0; df < 8; ++df) uacc[rf][df][reg] *= f;
            }

        int rem = l2v - j0; if (rem > JT) rem = JT;
        int njc = (rem + 31) / 32;
        for (int jc = 0; jc < njc; ++jc) {
            int jb = j0 + jc * 32;
            #pragma unroll
            for (int p = 0; p < 2; ++p) {
                const u16* src = p ? tl : th;
                uint4 pv[8];
                #pragma unroll
                for (int g = 0; g < 8; ++g) {
                    int dr = (tid >> 2) + g * 128, s = tid & 3;
                    pv[g] = *(const uint4*)&src[(size_t)dr * T2 + jb + s * 8];
                }
                __syncthreads();
                #pragma unroll
                for (int g = 0; g < 8; ++g) {
                    int dr = (tid >> 2) + g * 128, s = tid & 3;
                    *(uint4*)&sStage[dr * 40 + s * 8] = pv[g];
                }
                __syncthreads();
                bf16x8 pah[2], pal[2];
                #pragma unroll
                for (int rf = 0; rf < 2; ++rf) {
                    const char* rowb = (const char*)&sS[rf * 16 + lr][0];
                    pah[rf] = *(const bf16x8*)(rowb + (size_t)(jc * 32 + lg * 8) * 2);
                    if (p == 0)
                        pal[rf] = *(const bf16x8*)(rowb + (size_t)(JT + jc * 32 + lg * 8) * 2);
                }
                #pragma unroll
                for (int df = 0; df < 8; ++df) {
                    bf16x8 vb = *(bf16x8*)&sStage[(w * 128 + df * 16 + lr) * 40 + lg * 8];
                    #pragma unroll
                    for (int rf = 0; rf < 2; ++rf) {
                        uacc[rf][df] = __builtin_amdgcn_mfma_f32_16x16x32_bf16(pah[rf], vb, uacc[rf][df], 0, 0, 0);
                        if (p == 0)
                            uacc[rf][df] = __builtin_amdgcn_mfma_f32_16x16x32_bf16(pal[rf], vb, uacc[rf][df], 0, 0, 0);
                    }
                }
            }
        }
        __syncthreads();
    }

    if (lane == 0) {
        #pragma unroll
        for (int i = 0; i < 4; ++i) sL[w * 4 + i] = l_[i];
    }
    __syncthreads();
    #pragma unroll
    for (int rf = 0; rf < 2; ++rf)
        #pragma unroll
        for (int reg = 0; reg < 4; ++reg) {
            int r = rf * 16 + 4 * lg + reg;
            float inv = 1.0f / sL[r];
            bool valid = (row0 + r) < l1v;
            #pragma unroll
            for (int df = 0; df < 8; ++df) {
                int d = w * 128 + df * 16 + lr;
                outTile[(size_t)r * DD + d] = valid ? uacc[rf][df][reg] * inv : 0.f;
            }
        }
}

extern "C" void kernel_launch(void* const* d_in, const int* in_sizes, int n_in,
                              void* d_out, int out_size, void* d_ws, size_t ws_size,
                              hipStream_t stream)
{
    const float* s1 = (const float*)d_in[0];
    const int* l1 = (const int*)d_in[1];
    const float* s2 = (const float*)d_in[2];
    const int* l2 = (const int*)d_in[3];
    float* outp = (float*)d_out;

    int B = in_sizes[1];
    size_t elems = (size_t)B * T2 * DD;
    size_t sp_bytes = (size_t)B * T1 * T2 * sizeof(float);     // 128 MB
    size_t t_bytes = elems * 2 * sizeof(u16);                  // 128 MB (hi+lo)

    if (ws_size >= sp_bytes + t_bytes) {
        float* SP = (float*)d_ws;
        u16* s2th = (u16*)((char*)d_ws + sp_bytes);
        u16* s2tl = s2th + elems;
        conv_transpose<<<dim3(DD / 64, T2 / 64, B), 256, 0, stream>>>(s2, l2, s2th, s2tl);
        gemm1_qk<<<dim3(B * 64), 256, 0, stream>>>(s1, l1, s2, l2, SP);
        softmax_rows<<<dim3(B * 32), 256, 0, stream>>>(SP, l1, l2);
        gemm2_pv<<<dim3(B * 64), 256, 0, stream>>>(SP, s2th, s2tl, l1, l2, outp);
    } else {
        u16* s2th = (u16*)d_ws;
        u16* s2tl = s2th + elems;
        conv_transpose<<<dim3(DD / 64, T2 / 64, B), 256, 0, stream>>>(s2, l2, s2th, s2tl);
        bidaf_mfma<<<dim3(B * 32), NTH, 0, stream>>>(s1, l1, s2, l2, s2th, s2tl, outp);
    }
}